// Round 1
// baseline (673.586 us; speedup 1.0000x reference)
//
#include <hip/hip_runtime.h>

#define HD __device__ __forceinline__

namespace {

constexpr int H = 1080, W = 1920, HW = H * W;
constexpr float FXc = 1000.0f, FYc = 1000.0f;
constexpr float D_COS = 0.867f, D_DIFF = 0.35f, D_Z = 0.05f, D_FARZ = 12.3f;

struct Stats {
  unsigned V, k, hb, cnt_before, t, cnt_lt;
  unsigned pad0, pad1;
  double S_all, S_lt;
};

struct F3 { float x, y, z; };
HD F3 fsub(F3 a, F3 b) { return {a.x - b.x, a.y - b.y, a.z - b.z}; }
HD float fdot(F3 a, F3 b) { return a.x * b.x + a.y * b.y + a.z * b.z; }
HD F3 fcross(F3 a, F3 b) {
  return {a.y * b.z - a.z * b.y, a.z * b.x - a.x * b.z, a.x * b.y - a.y * b.x};
}

HD F3 mkpt(int j, float d) {
  int v = j / W;
  int u = j - v * W;
  float ad = fabsf(d);
  F3 p;
  p.x = (float)(u - W / 2) * ad / FXc;
  p.y = (float)(v - H / 2) * ad / FYc;
  p.z = d;
  return p;
}

__global__ void vnl_main(const float* __restrict__ pred, const float* __restrict__ gt,
                         const int* __restrict__ p1, const int* __restrict__ p2,
                         const int* __restrict__ p3, unsigned* __restrict__ ubits,
                         unsigned* __restrict__ hist_hi, Stats* st, int G, int N) {
  int i = blockIdx.x * blockDim.x + threadIdx.x;
  float lv = 0.f;
  bool masked = false;
  unsigned bits = 0xFFFFFFFFu;
  if (i < N) {
    int b = i / G;
    int g = i - b * G;
    int j1 = p1[g], j2 = p2[g], j3 = p3[g];
    const float* gb = gt + (size_t)b * HW;
    const float* pb = pred + (size_t)b * HW;
    F3 A = mkpt(j1, gb[j1]);
    F3 Bp = mkpt(j2, gb[j2]);
    F3 C = mkpt(j3, gb[j3]);
    F3 e12 = fsub(Bp, A), e13 = fsub(C, A), e23 = fsub(C, Bp);
    F3 ev[3] = {e12, e13, e23};
    float nn[3] = {sqrtf(fdot(ev[0], ev[0])), sqrtf(fdot(ev[1], ev[1])),
                   sqrtf(fdot(ev[2], ev[2]))};
    int cnt = 0;
#pragma unroll
    for (int a = 0; a < 3; a++)
#pragma unroll
      for (int c = 0; c < 3; c++) {
        float ne = fdot(ev[a], ev[c]) / (nn[a] * nn[c] + 1e-8f);
        if (ne > D_COS || ne < -D_COS) cnt++;
      }
    bool mask_cos = cnt > 3;
    bool mask_pad = (A.z > D_Z) && (Bp.z > D_Z) && (C.z > D_Z);
    bool mask_far = (A.z < D_FARZ) && (Bp.z < D_FARZ) && (C.z < D_FARZ);
    bool mx = fabsf(e12.x) < D_DIFF || fabsf(e13.x) < D_DIFF || fabsf(e23.x) < D_DIFF;
    bool my = fabsf(e12.y) < D_DIFF || fabsf(e13.y) < D_DIFF || fabsf(e23.y) < D_DIFF;
    bool mz = fabsf(e12.z) < D_DIFF || fabsf(e13.z) < D_DIFF || fabsf(e23.z) < D_DIFF;
    masked = mask_pad && mask_far && !((mx && my && mz) || mask_cos);

    // pred points, with the reference's z_zero broadcast semantics:
    // if point c's z == 0, coordinate c of ALL points := 1e-4
    F3 P0 = mkpt(j1, pb[j1]);
    F3 P1 = mkpt(j2, pb[j2]);
    F3 P2 = mkpt(j3, pb[j3]);
    if (P0.z == 0.f) { P0.x = 1e-4f; P1.x = 1e-4f; P2.x = 1e-4f; }
    if (P1.z == 0.f) { P0.y = 1e-4f; P1.y = 1e-4f; P2.y = 1e-4f; }
    if (P2.z == 0.f) { P0.z = 1e-4f; P1.z = 1e-4f; P2.z = 1e-4f; }

    F3 ngt = fcross(e12, e13);
    float lg = sqrtf(fdot(ngt, ngt));
    lg += (lg == 0.f) ? 0.01f : 0.f;
    F3 q12 = fsub(P1, P0), q13 = fsub(P2, P0);
    F3 npr = fcross(q12, q13);
    float lp = sqrtf(fdot(npr, npr));
    lp += (lp == 0.f) ? 0.01f : 0.f;
    float l = fabsf(ngt.x / lg - npr.x / lp) + fabsf(ngt.y / lg - npr.y / lp) +
              fabsf(ngt.z / lg - npr.z / lp);
    if (masked) { lv = l; bits = __float_as_uint(l); }
  }
  if (i < N) ubits[i] = bits;
  if (masked) atomicAdd(&hist_hi[bits >> 16], 1u);

  __shared__ float red[256];
  red[threadIdx.x] = lv;
  __syncthreads();
  for (int off = 128; off > 0; off >>= 1) {
    if (threadIdx.x < (unsigned)off) red[threadIdx.x] += red[threadIdx.x + off];
    __syncthreads();
  }
  if (threadIdx.x == 0 && red[0] != 0.f) atomicAdd(&st->S_all, (double)red[0]);
}

// level 0: scan hist_hi -> V, k=V/4, hb (bucket containing k-th smallest), cnt_before
// level 1: scan hist_lo -> t (exact k-th smallest bits), cnt_lt = #{< t}
__global__ void vnl_select(const unsigned* __restrict__ hist, Stats* st, int level) {
  constexpr int T = 1024, BPT = 65536 / T;  // 64 bins per thread
  __shared__ unsigned tsum[T];
  __shared__ unsigned long long best;
  int tid = threadIdx.x;
  int b0 = tid * BPT;
  unsigned s = 0;
#pragma unroll
  for (int j = 0; j < BPT; ++j) s += hist[b0 + j];
  tsum[tid] = s;
  __syncthreads();
  for (int off = 1; off < T; off <<= 1) {
    unsigned v = (tid >= off) ? tsum[tid - off] : 0u;
    __syncthreads();
    tsum[tid] += v;
    __syncthreads();
  }
  unsigned total = tsum[T - 1];
  unsigned base = tsum[tid] - s;  // exclusive prefix of this thread's range
  unsigned kk = (level == 0) ? (total >> 2) : (st->k - st->cnt_before);
  if (tid == 0) best = ~0ull;
  __syncthreads();
  unsigned run = base;
  for (int j = 0; j < BPT; ++j) {
    unsigned c = hist[b0 + j];
    if (run + c >= kk) {
      atomicMin(&best, ((unsigned long long)(b0 + j) << 32) | (unsigned long long)run);
      break;
    }
    run += c;
  }
  __syncthreads();
  if (tid == 0) {
    unsigned bb = (unsigned)(best >> 32);
    unsigned P = (unsigned)(best & 0xFFFFFFFFu);
    if (level == 0) {
      st->V = total;
      st->k = total >> 2;
      st->hb = bb;
      st->cnt_before = P;
    } else {
      st->t = (st->hb << 16) | bb;
      st->cnt_lt = st->cnt_before + P;
    }
  }
}

__global__ void vnl_histlo(const unsigned* __restrict__ ubits, unsigned* __restrict__ hist_lo,
                           const Stats* __restrict__ st, int N) {
  int i = blockIdx.x * blockDim.x + threadIdx.x;
  if (i >= N) return;
  unsigned hb = st->hb;
  unsigned v = ubits[i];
  if ((v >> 16) == hb) atomicAdd(&hist_lo[v & 0xFFFFu], 1u);
}

__global__ void vnl_sumlt(const unsigned* __restrict__ ubits, Stats* st, int N) {
  int i = blockIdx.x * blockDim.x + threadIdx.x;
  unsigned t = st->t;
  float lv = 0.f;
  if (i < N) {
    unsigned v = ubits[i];
    if (v < t) lv = __uint_as_float(v);
  }
  __shared__ float red[256];
  red[threadIdx.x] = lv;
  __syncthreads();
  for (int off = 128; off > 0; off >>= 1) {
    if (threadIdx.x < (unsigned)off) red[threadIdx.x] += red[threadIdx.x + off];
    __syncthreads();
  }
  if (threadIdx.x == 0 && red[0] != 0.f) atomicAdd(&st->S_lt, (double)red[0]);
}

__global__ void vnl_final(const Stats* __restrict__ st, float* __restrict__ out) {
  unsigned V = st->V, k = st->k;
  float res = 0.f;
  if (V > 0) {
    double tf = (double)__uint_as_float(st->t);
    double sum_keep = st->S_all - st->S_lt - (double)(k - st->cnt_lt) * tf;
    unsigned denom = V - k;
    if (denom < 1) denom = 1;
    res = (float)(sum_keep / (double)denom);
  }
  out[0] = res;
}

}  // namespace

extern "C" void kernel_launch(void* const* d_in, const int* in_sizes, int n_in,
                              void* d_out, int out_size, void* d_ws, size_t ws_size,
                              hipStream_t stream) {
  const float* pred = (const float*)d_in[0];
  const float* gt = (const float*)d_in[1];
  const int* p1 = (const int*)d_in[2];
  const int* p2 = (const int*)d_in[3];
  const int* p3 = (const int*)d_in[4];
  int B = in_sizes[0] / HW;
  int G = in_sizes[2];
  int N = B * G;

  char* ws = (char*)d_ws;
  size_t off = ((size_t)N * 4 + 255) & ~(size_t)255;
  unsigned* ubits = (unsigned*)ws;
  unsigned* hist_hi = (unsigned*)(ws + off);
  unsigned* hist_lo = (unsigned*)(ws + off + 65536 * 4);
  Stats* st = (Stats*)(ws + off + 2 * 65536 * 4);

  hipMemsetAsync(ws + off, 0, 2 * 65536 * 4 + sizeof(Stats), stream);

  int blocks = (N + 255) / 256;
  vnl_main<<<blocks, 256, 0, stream>>>(pred, gt, p1, p2, p3, ubits, hist_hi, st, G, N);
  vnl_select<<<1, 1024, 0, stream>>>(hist_hi, st, 0);
  vnl_histlo<<<blocks, 256, 0, stream>>>(ubits, hist_lo, st, N);
  vnl_select<<<1, 1024, 0, stream>>>(hist_lo, st, 1);
  vnl_sumlt<<<blocks, 256, 0, stream>>>(ubits, st, N);
  vnl_final<<<1, 1, 0, stream>>>(st, (float*)d_out);
}

// Round 2
// 632.834 us; speedup vs baseline: 1.0644x; 1.0644x over previous
//
#include <hip/hip_runtime.h>

#define HD __device__ __forceinline__

namespace {

constexpr int H = 1080, W = 1920, HW = H * W;
constexpr float FXc = 1000.0f, FYc = 1000.0f;
constexpr float D_COS = 0.867f, D_DIFF = 0.35f, D_Z = 0.05f, D_FARZ = 12.3f;

struct Stats {
  unsigned V, k, hb, cnt_before, t, cnt_lt;
  unsigned pad0, pad1;
  double S_all, S_lt;
};

struct F3 { float x, y, z; };
HD F3 fsub(F3 a, F3 b) { return {a.x - b.x, a.y - b.y, a.z - b.z}; }
HD float fdot(F3 a, F3 b) { return a.x * b.x + a.y * b.y + a.z * b.z; }
HD F3 fcross(F3 a, F3 b) {
  return {a.y * b.z - a.z * b.y, a.z * b.x - a.x * b.z, a.x * b.y - a.y * b.x};
}

HD F3 mkpt2(float ux, float vy, float d) {
  float ad = fabsf(d);
  F3 p;
  p.x = ux * ad / FXc;
  p.y = vy * ad / FYc;
  p.z = d;
  return p;
}

HD F3 mkpt(int j, float d) {
  int v = j / W;
  int u = j - v * W;
  return mkpt2((float)(u - W / 2), (float)(v - H / 2), d);
}

// Core per-(group,batch) computation. Returns loss bits (0xFFFFFFFF if unmasked).
HD unsigned vnl_elem(F3 A, F3 Bp, F3 C, F3 P0, F3 P1, F3 P2, float* lv) {
  F3 e12 = fsub(Bp, A), e13 = fsub(C, A), e23 = fsub(C, Bp);
  F3 ev[3] = {e12, e13, e23};
  float nn[3] = {sqrtf(fdot(ev[0], ev[0])), sqrtf(fdot(ev[1], ev[1])),
                 sqrtf(fdot(ev[2], ev[2]))};
  int cnt = 0;
#pragma unroll
  for (int a = 0; a < 3; a++)
#pragma unroll
    for (int c = 0; c < 3; c++) {
      float ne = fdot(ev[a], ev[c]) / (nn[a] * nn[c] + 1e-8f);
      if (ne > D_COS || ne < -D_COS) cnt++;
    }
  bool mask_cos = cnt > 3;
  bool mask_pad = (A.z > D_Z) && (Bp.z > D_Z) && (C.z > D_Z);
  bool mask_far = (A.z < D_FARZ) && (Bp.z < D_FARZ) && (C.z < D_FARZ);
  bool mx = fabsf(e12.x) < D_DIFF || fabsf(e13.x) < D_DIFF || fabsf(e23.x) < D_DIFF;
  bool my = fabsf(e12.y) < D_DIFF || fabsf(e13.y) < D_DIFF || fabsf(e23.y) < D_DIFF;
  bool mz = fabsf(e12.z) < D_DIFF || fabsf(e13.z) < D_DIFF || fabsf(e23.z) < D_DIFF;
  bool masked = mask_pad && mask_far && !((mx && my && mz) || mask_cos);

  // reference's z_zero broadcast semantics:
  // if point c's z == 0, coordinate c of ALL points := 1e-4
  if (P0.z == 0.f) { P0.x = 1e-4f; P1.x = 1e-4f; P2.x = 1e-4f; }
  if (P1.z == 0.f) { P0.y = 1e-4f; P1.y = 1e-4f; P2.y = 1e-4f; }
  if (P2.z == 0.f) { P0.z = 1e-4f; P1.z = 1e-4f; P2.z = 1e-4f; }

  F3 ngt = fcross(e12, e13);
  float lg = sqrtf(fdot(ngt, ngt));
  lg += (lg == 0.f) ? 0.01f : 0.f;
  F3 q12 = fsub(P1, P0), q13 = fsub(P2, P0);
  F3 npr = fcross(q12, q13);
  float lp = sqrtf(fdot(npr, npr));
  lp += (lp == 0.f) ? 0.01f : 0.f;
  float l = fabsf(ngt.x / lg - npr.x / lp) + fabsf(ngt.y / lg - npr.y / lp) +
            fabsf(ngt.z / lg - npr.z / lp);
  if (masked) { *lv = l; return __float_as_uint(l); }
  *lv = 0.f;
  return 0xFFFFFFFFu;
}

// ---- packed fast path (B == 4) ----
// pack depth to [HW][8]: {gt[b=0..3][j], pred[b=0..3][j]} -> 32B per pixel.
__global__ void vnl_pack(const float* __restrict__ pred, const float* __restrict__ gt,
                         float4* __restrict__ pk) {
  int j = blockIdx.x * blockDim.x + threadIdx.x;
  if (j >= HW) return;
  float4 g = {gt[j], gt[HW + j], gt[2 * HW + j], gt[3 * HW + j]};
  float4 p = {pred[j], pred[HW + j], pred[2 * HW + j], pred[3 * HW + j]};
  pk[2 * j] = g;
  pk[2 * j + 1] = p;
}

__global__ void vnl_main4(const float4* __restrict__ pk, const int* __restrict__ p1,
                          const int* __restrict__ p2, const int* __restrict__ p3,
                          unsigned* __restrict__ ubits, unsigned* __restrict__ hist_hi,
                          Stats* st, int G) {
  int g = blockIdx.x * blockDim.x + threadIdx.x;
  float lsum = 0.f;
  if (g < G) {
    int j[3] = {p1[g], p2[g], p3[g]};
    float gd[3][4], pd[3][4];
    float ux[3], vy[3];
#pragma unroll
    for (int c = 0; c < 3; ++c) {
      int jj = j[c];
      float4 gv = pk[2 * jj];
      float4 pv = pk[2 * jj + 1];
      *(float4*)gd[c] = gv;
      *(float4*)pd[c] = pv;
      int vrow = jj / W;
      int ucol = jj - vrow * W;
      ux[c] = (float)(ucol - W / 2);
      vy[c] = (float)(vrow - H / 2);
    }
#pragma unroll
    for (int b = 0; b < 4; ++b) {
      F3 A = mkpt2(ux[0], vy[0], gd[0][b]);
      F3 Bp = mkpt2(ux[1], vy[1], gd[1][b]);
      F3 C = mkpt2(ux[2], vy[2], gd[2][b]);
      F3 P0 = mkpt2(ux[0], vy[0], pd[0][b]);
      F3 P1 = mkpt2(ux[1], vy[1], pd[1][b]);
      F3 P2 = mkpt2(ux[2], vy[2], pd[2][b]);
      float lv;
      unsigned bits = vnl_elem(A, Bp, C, P0, P1, P2, &lv);
      if (bits != 0xFFFFFFFFu) {
        lsum += lv;
        atomicAdd(&hist_hi[bits >> 16], 1u);
      }
      ubits[b * G + g] = bits;
    }
  }
  __shared__ float red[256];
  red[threadIdx.x] = lsum;
  __syncthreads();
  for (int off = 128; off > 0; off >>= 1) {
    if (threadIdx.x < (unsigned)off) red[threadIdx.x] += red[threadIdx.x + off];
    __syncthreads();
  }
  if (threadIdx.x == 0 && red[0] != 0.f) atomicAdd(&st->S_all, (double)red[0]);
}

// ---- fallback scalar path (any B) ----
__global__ void vnl_main(const float* __restrict__ pred, const float* __restrict__ gt,
                         const int* __restrict__ p1, const int* __restrict__ p2,
                         const int* __restrict__ p3, unsigned* __restrict__ ubits,
                         unsigned* __restrict__ hist_hi, Stats* st, int G, int N) {
  int i = blockIdx.x * blockDim.x + threadIdx.x;
  float lv = 0.f;
  unsigned bits = 0xFFFFFFFFu;
  if (i < N) {
    int b = i / G;
    int g = i - b * G;
    int j1 = p1[g], j2 = p2[g], j3 = p3[g];
    const float* gb = gt + (size_t)b * HW;
    const float* pb = pred + (size_t)b * HW;
    bits = vnl_elem(mkpt(j1, gb[j1]), mkpt(j2, gb[j2]), mkpt(j3, gb[j3]),
                    mkpt(j1, pb[j1]), mkpt(j2, pb[j2]), mkpt(j3, pb[j3]), &lv);
    ubits[i] = bits;
    if (bits != 0xFFFFFFFFu) atomicAdd(&hist_hi[bits >> 16], 1u);
  }
  __shared__ float red[256];
  red[threadIdx.x] = lv;
  __syncthreads();
  for (int off = 128; off > 0; off >>= 1) {
    if (threadIdx.x < (unsigned)off) red[threadIdx.x] += red[threadIdx.x + off];
    __syncthreads();
  }
  if (threadIdx.x == 0 && red[0] != 0.f) atomicAdd(&st->S_all, (double)red[0]);
}

// level 0: scan hist_hi -> V, k=V/4, hb (bucket containing k-th smallest), cnt_before
// level 1: scan hist_lo -> t (exact k-th smallest bits), cnt_lt = #{< t}
__global__ void vnl_select(const unsigned* __restrict__ hist, Stats* st, int level) {
  constexpr int T = 1024, BPT = 65536 / T;  // 64 bins per thread
  __shared__ unsigned tsum[T];
  __shared__ unsigned long long best;
  int tid = threadIdx.x;
  int b0 = tid * BPT;
  unsigned s = 0;
#pragma unroll
  for (int j = 0; j < BPT; ++j) s += hist[b0 + j];
  tsum[tid] = s;
  __syncthreads();
  for (int off = 1; off < T; off <<= 1) {
    unsigned v = (tid >= off) ? tsum[tid - off] : 0u;
    __syncthreads();
    tsum[tid] += v;
    __syncthreads();
  }
  unsigned total = tsum[T - 1];
  unsigned base = tsum[tid] - s;  // exclusive prefix of this thread's range
  unsigned kk = (level == 0) ? (total >> 2) : (st->k - st->cnt_before);
  if (tid == 0) best = ~0ull;
  __syncthreads();
  unsigned run = base;
  for (int j = 0; j < BPT; ++j) {
    unsigned c = hist[b0 + j];
    if (run + c >= kk) {
      atomicMin(&best, ((unsigned long long)(b0 + j) << 32) | (unsigned long long)run);
      break;
    }
    run += c;
  }
  __syncthreads();
  if (tid == 0) {
    unsigned bb = (unsigned)(best >> 32);
    unsigned P = (unsigned)(best & 0xFFFFFFFFu);
    if (level == 0) {
      st->V = total;
      st->k = total >> 2;
      st->hb = bb;
      st->cnt_before = P;
    } else {
      st->t = (st->hb << 16) | bb;
      st->cnt_lt = st->cnt_before + P;
    }
  }
}

__global__ void vnl_histlo(const unsigned* __restrict__ ubits, unsigned* __restrict__ hist_lo,
                           const Stats* __restrict__ st, int N) {
  int i = (blockIdx.x * blockDim.x + threadIdx.x) * 4;
  unsigned hb = st->hb;
  if (i + 3 < N) {
    uint4 v = *(const uint4*)(ubits + i);
    if ((v.x >> 16) == hb) atomicAdd(&hist_lo[v.x & 0xFFFFu], 1u);
    if ((v.y >> 16) == hb) atomicAdd(&hist_lo[v.y & 0xFFFFu], 1u);
    if ((v.z >> 16) == hb) atomicAdd(&hist_lo[v.z & 0xFFFFu], 1u);
    if ((v.w >> 16) == hb) atomicAdd(&hist_lo[v.w & 0xFFFFu], 1u);
  } else {
    for (; i < N; ++i) {
      unsigned v = ubits[i];
      if ((v >> 16) == hb) atomicAdd(&hist_lo[v & 0xFFFFu], 1u);
    }
  }
}

__global__ void vnl_sumlt(const unsigned* __restrict__ ubits, Stats* st, int N) {
  int i = (blockIdx.x * blockDim.x + threadIdx.x) * 4;
  unsigned t = st->t;
  float lv = 0.f;
  if (i + 3 < N) {
    uint4 v = *(const uint4*)(ubits + i);
    if (v.x < t) lv += __uint_as_float(v.x);
    if (v.y < t) lv += __uint_as_float(v.y);
    if (v.z < t) lv += __uint_as_float(v.z);
    if (v.w < t) lv += __uint_as_float(v.w);
  } else {
    for (; i < N; ++i) {
      unsigned v = ubits[i];
      if (v < t) lv += __uint_as_float(v);
    }
  }
  __shared__ float red[256];
  red[threadIdx.x] = lv;
  __syncthreads();
  for (int off = 128; off > 0; off >>= 1) {
    if (threadIdx.x < (unsigned)off) red[threadIdx.x] += red[threadIdx.x + off];
    __syncthreads();
  }
  if (threadIdx.x == 0 && red[0] != 0.f) atomicAdd(&st->S_lt, (double)red[0]);
}

__global__ void vnl_final(const Stats* __restrict__ st, float* __restrict__ out) {
  unsigned V = st->V, k = st->k;
  float res = 0.f;
  if (V > 0) {
    double tf = (double)__uint_as_float(st->t);
    double sum_keep = st->S_all - st->S_lt - (double)(k - st->cnt_lt) * tf;
    unsigned denom = V - k;
    if (denom < 1) denom = 1;
    res = (float)(sum_keep / (double)denom);
  }
  out[0] = res;
}

}  // namespace

extern "C" void kernel_launch(void* const* d_in, const int* in_sizes, int n_in,
                              void* d_out, int out_size, void* d_ws, size_t ws_size,
                              hipStream_t stream) {
  const float* pred = (const float*)d_in[0];
  const float* gt = (const float*)d_in[1];
  const int* p1 = (const int*)d_in[2];
  const int* p2 = (const int*)d_in[3];
  const int* p3 = (const int*)d_in[4];
  int B = in_sizes[0] / HW;
  int G = in_sizes[2];
  int N = B * G;

  char* ws = (char*)d_ws;
  size_t pk_bytes = (size_t)HW * 32;
  size_t ub_bytes = ((size_t)N * 4 + 255) & ~(size_t)255;
  size_t need_fast = pk_bytes + ub_bytes + 2 * 65536 * 4 + sizeof(Stats) + 256;
  bool fast = (B == 4) && (ws_size >= need_fast);

  unsigned* ubits;
  unsigned* hist_hi;
  float4* pk = nullptr;
  if (fast) {
    pk = (float4*)ws;
    ubits = (unsigned*)(ws + pk_bytes);
    hist_hi = (unsigned*)(ws + pk_bytes + ub_bytes);
  } else {
    ubits = (unsigned*)ws;
    hist_hi = (unsigned*)(ws + ub_bytes);
  }
  unsigned* hist_lo = hist_hi + 65536;
  Stats* st = (Stats*)(hist_lo + 65536);

  hipMemsetAsync(hist_hi, 0, 2 * 65536 * 4 + sizeof(Stats), stream);

  int blocksN = (N + 255) / 256;
  int blocks4 = (N / 4 + 255) / 256 + 1;
  if (fast) {
    vnl_pack<<<(HW + 255) / 256, 256, 0, stream>>>(pred, gt, pk);
    vnl_main4<<<(G + 255) / 256, 256, 0, stream>>>(pk, p1, p2, p3, ubits, hist_hi, st, G);
  } else {
    vnl_main<<<blocksN, 256, 0, stream>>>(pred, gt, p1, p2, p3, ubits, hist_hi, st, G, N);
  }
  vnl_select<<<1, 1024, 0, stream>>>(hist_hi, st, 0);
  vnl_histlo<<<blocks4, 256, 0, stream>>>(ubits, hist_lo, st, N);
  vnl_select<<<1, 1024, 0, stream>>>(hist_lo, st, 1);
  vnl_sumlt<<<blocks4, 256, 0, stream>>>(ubits, st, N);
  vnl_final<<<1, 1, 0, stream>>>(st, (float*)d_out);
}

// Round 3
// 179.322 us; speedup vs baseline: 3.7563x; 3.5290x over previous
//
#include <hip/hip_runtime.h>

#define HD __device__ __forceinline__

namespace {

constexpr int H = 1080, W = 1920, HW = H * W;
constexpr float FXc = 1000.0f, FYc = 1000.0f;
constexpr float D_COS = 0.867f, D_DIFF = 0.35f, D_Z = 0.05f, D_FARZ = 12.3f;
constexpr int NB_HIST = 512;  // fixed grid for hist/sum passes

struct Stats {
  unsigned V, k, prefix, kk_rem, cnt_lt, pad0, pad1, pad2;
  double S_all;
};

struct F3 { float x, y, z; };
HD F3 fsub(F3 a, F3 b) { return {a.x - b.x, a.y - b.y, a.z - b.z}; }
HD float fdot(F3 a, F3 b) { return a.x * b.x + a.y * b.y + a.z * b.z; }
HD F3 fcross(F3 a, F3 b) {
  return {a.y * b.z - a.z * b.y, a.z * b.x - a.x * b.z, a.x * b.y - a.y * b.x};
}

HD F3 mkpt2(float ux, float vy, float d) {
  float ad = fabsf(d);
  F3 p;
  p.x = ux * ad / FXc;
  p.y = vy * ad / FYc;
  p.z = d;
  return p;
}

HD F3 mkpt(int j, float d) {
  int v = j / W;
  int u = j - v * W;
  return mkpt2((float)(u - W / 2), (float)(v - H / 2), d);
}

// Core per-(group,batch) computation. Returns loss bits (0xFFFFFFFF if unmasked).
HD unsigned vnl_elem(F3 A, F3 Bp, F3 C, F3 P0, F3 P1, F3 P2, float* lv) {
  F3 e12 = fsub(Bp, A), e13 = fsub(C, A), e23 = fsub(C, Bp);
  F3 ev[3] = {e12, e13, e23};
  float nn[3] = {sqrtf(fdot(ev[0], ev[0])), sqrtf(fdot(ev[1], ev[1])),
                 sqrtf(fdot(ev[2], ev[2]))};
  int cnt = 0;
#pragma unroll
  for (int a = 0; a < 3; a++)
#pragma unroll
    for (int c = 0; c < 3; c++) {
      float ne = fdot(ev[a], ev[c]) / (nn[a] * nn[c] + 1e-8f);
      if (ne > D_COS || ne < -D_COS) cnt++;
    }
  bool mask_cos = cnt > 3;
  bool mask_pad = (A.z > D_Z) && (Bp.z > D_Z) && (C.z > D_Z);
  bool mask_far = (A.z < D_FARZ) && (Bp.z < D_FARZ) && (C.z < D_FARZ);
  bool mx = fabsf(e12.x) < D_DIFF || fabsf(e13.x) < D_DIFF || fabsf(e23.x) < D_DIFF;
  bool my = fabsf(e12.y) < D_DIFF || fabsf(e13.y) < D_DIFF || fabsf(e23.y) < D_DIFF;
  bool mz = fabsf(e12.z) < D_DIFF || fabsf(e13.z) < D_DIFF || fabsf(e23.z) < D_DIFF;
  bool masked = mask_pad && mask_far && !((mx && my && mz) || mask_cos);

  // reference's z_zero broadcast semantics:
  // if point c's z == 0, coordinate c of ALL points := 1e-4
  if (P0.z == 0.f) { P0.x = 1e-4f; P1.x = 1e-4f; P2.x = 1e-4f; }
  if (P1.z == 0.f) { P0.y = 1e-4f; P1.y = 1e-4f; P2.y = 1e-4f; }
  if (P2.z == 0.f) { P0.z = 1e-4f; P1.z = 1e-4f; P2.z = 1e-4f; }

  F3 ngt = fcross(e12, e13);
  float lg = sqrtf(fdot(ngt, ngt));
  lg += (lg == 0.f) ? 0.01f : 0.f;
  F3 q12 = fsub(P1, P0), q13 = fsub(P2, P0);
  F3 npr = fcross(q12, q13);
  float lp = sqrtf(fdot(npr, npr));
  lp += (lp == 0.f) ? 0.01f : 0.f;
  float l = fabsf(ngt.x / lg - npr.x / lp) + fabsf(ngt.y / lg - npr.y / lp) +
            fabsf(ngt.z / lg - npr.z / lp);
  if (masked) { *lv = l; return __float_as_uint(l); }
  *lv = 0.f;
  return 0xFFFFFFFFu;
}

// ---- packed fast path (B == 4) ----
__global__ void vnl_pack(const float* __restrict__ pred, const float* __restrict__ gt,
                         float4* __restrict__ pk) {
  int j = blockIdx.x * blockDim.x + threadIdx.x;
  if (j >= HW) return;
  float4 g = {gt[j], gt[HW + j], gt[2 * HW + j], gt[3 * HW + j]};
  float4 p = {pred[j], pred[HW + j], pred[2 * HW + j], pred[3 * HW + j]};
  pk[2 * j] = g;
  pk[2 * j + 1] = p;
}

__global__ void vnl_main4(const float4* __restrict__ pk, const int* __restrict__ p1,
                          const int* __restrict__ p2, const int* __restrict__ p3,
                          unsigned* __restrict__ ubits, float* __restrict__ partials,
                          int G) {
  int g = blockIdx.x * blockDim.x + threadIdx.x;
  float lsum = 0.f;
  if (g < G) {
    int j[3] = {p1[g], p2[g], p3[g]};
    float gd[3][4], pd[3][4];
    float ux[3], vy[3];
#pragma unroll
    for (int c = 0; c < 3; ++c) {
      int jj = j[c];
      float4 gv = pk[2 * jj];
      float4 pv = pk[2 * jj + 1];
      *(float4*)gd[c] = gv;
      *(float4*)pd[c] = pv;
      int vrow = jj / W;
      int ucol = jj - vrow * W;
      ux[c] = (float)(ucol - W / 2);
      vy[c] = (float)(vrow - H / 2);
    }
#pragma unroll
    for (int b = 0; b < 4; ++b) {
      F3 A = mkpt2(ux[0], vy[0], gd[0][b]);
      F3 Bp = mkpt2(ux[1], vy[1], gd[1][b]);
      F3 C = mkpt2(ux[2], vy[2], gd[2][b]);
      F3 P0 = mkpt2(ux[0], vy[0], pd[0][b]);
      F3 P1 = mkpt2(ux[1], vy[1], pd[1][b]);
      F3 P2 = mkpt2(ux[2], vy[2], pd[2][b]);
      float lv;
      unsigned bits = vnl_elem(A, Bp, C, P0, P1, P2, &lv);
      lsum += lv;
      ubits[b * G + g] = bits;
    }
  }
  __shared__ float red[256];
  red[threadIdx.x] = lsum;
  __syncthreads();
  for (int off = 128; off > 0; off >>= 1) {
    if (threadIdx.x < (unsigned)off) red[threadIdx.x] += red[threadIdx.x + off];
    __syncthreads();
  }
  if (threadIdx.x == 0) partials[blockIdx.x] = red[0];
}

// ---- fallback scalar path (any B) ----
__global__ void vnl_main(const float* __restrict__ pred, const float* __restrict__ gt,
                         const int* __restrict__ p1, const int* __restrict__ p2,
                         const int* __restrict__ p3, unsigned* __restrict__ ubits,
                         float* __restrict__ partials, int G, int N) {
  int i = blockIdx.x * blockDim.x + threadIdx.x;
  float lv = 0.f;
  if (i < N) {
    int b = i / G;
    int g = i - b * G;
    int j1 = p1[g], j2 = p2[g], j3 = p3[g];
    const float* gb = gt + (size_t)b * HW;
    const float* pb = pred + (size_t)b * HW;
    unsigned bits = vnl_elem(mkpt(j1, gb[j1]), mkpt(j2, gb[j2]), mkpt(j3, gb[j3]),
                             mkpt(j1, pb[j1]), mkpt(j2, pb[j2]), mkpt(j3, pb[j3]), &lv);
    ubits[i] = bits;
  }
  __shared__ float red[256];
  red[threadIdx.x] = lv;
  __syncthreads();
  for (int off = 128; off > 0; off >>= 1) {
    if (threadIdx.x < (unsigned)off) red[threadIdx.x] += red[threadIdx.x + off];
    __syncthreads();
  }
  if (threadIdx.x == 0) partials[blockIdx.x] = red[0];
}

// ---- 8-bit MSB-first radix select, 4 passes, no global atomics ----
// Pass `pass`: histogram of digit (bits >> (24-8*pass)) & 0xFF over elements whose
// higher bits match st->prefix. 16 lane-replicated LDS sub-histograms.
__global__ void vnl_hist(const unsigned* __restrict__ ubits, unsigned* __restrict__ histmat,
                         const Stats* __restrict__ st, int N, int pass) {
  __shared__ unsigned h[256 * 16];
  int tid = threadIdx.x;
  for (int i = tid; i < 256 * 16; i += 256) h[i] = 0;
  __syncthreads();
  int shift = 24 - 8 * pass;
  bool all = (pass == 0);
  unsigned pfx = all ? 0u : (st->prefix >> (shift + 8));
  int sub = tid & 15;
  for (int i = blockIdx.x * blockDim.x + tid; i < N; i += gridDim.x * blockDim.x) {
    unsigned v = ubits[i];
    if (all || (v >> (shift + 8)) == pfx)
      atomicAdd(&h[(((v >> shift) & 0xFFu) << 4) + sub], 1u);
  }
  __syncthreads();
  unsigned s = 0;
#pragma unroll
  for (int j = 0; j < 16; ++j) s += h[(tid << 4) + j];
  histmat[blockIdx.x * 256 + tid] = s;
}

// Single block, 256 threads. Reduces histmat rows, scans, picks digit.
// level 0 additionally computes V, k and reduces S_all partials.
__global__ void vnl_scan(const unsigned* __restrict__ histmat, Stats* st, int level,
                         const float* __restrict__ partials, int nPartials) {
  __shared__ unsigned cum[256];
  __shared__ double sred[256];
  int tid = threadIdx.x;
  unsigned s = 0;
  for (int r = 0; r < NB_HIST; ++r) s += histmat[r * 256 + tid];
  cum[tid] = s;
  if (level == 0) {
    double ps = 0.0;
    for (int i = tid; i < nPartials; i += 256) ps += (double)partials[i];
    sred[tid] = ps;
  }
  __syncthreads();
  for (int off = 1; off < 256; off <<= 1) {
    unsigned v = (tid >= off) ? cum[tid - off] : 0u;
    __syncthreads();
    cum[tid] += v;
    __syncthreads();
  }
  if (level == 0) {
    for (int off = 128; off > 0; off >>= 1) {
      if (tid < off) sred[tid] += sred[tid + off];
      __syncthreads();
    }
  }
  unsigned kk;
  if (level == 0) {
    unsigned V = cum[254];  // bin 255 at level 0 holds only unmasked sentinels
    kk = V >> 2;
    if (tid == 0) {
      st->V = V;
      st->k = kk;
      st->S_all = sred[0];
    }
  } else {
    kk = st->kk_rem;
  }
  unsigned prev = (tid == 0) ? 0u : cum[tid - 1];
  bool win = (kk >= 1) && (cum[tid] >= kk) && (prev < kk);
  if (win) {  // exactly one thread (none if kk==0 -> state stays: prefix 0, cnt_lt 0)
    int shift = 24 - 8 * level;
    st->cnt_lt += prev;
    st->kk_rem = kk - prev;
    st->prefix |= ((unsigned)tid) << shift;
  }
}

__global__ void vnl_sumlt(const unsigned* __restrict__ ubits, const Stats* __restrict__ st,
                          float* __restrict__ partials2, int N) {
  unsigned t = st->prefix;
  float lv = 0.f;
  for (int i = blockIdx.x * blockDim.x + threadIdx.x; i < N; i += gridDim.x * blockDim.x) {
    unsigned v = ubits[i];
    if (v < t) lv += __uint_as_float(v);
  }
  __shared__ float red[256];
  red[threadIdx.x] = lv;
  __syncthreads();
  for (int off = 128; off > 0; off >>= 1) {
    if (threadIdx.x < (unsigned)off) red[threadIdx.x] += red[threadIdx.x + off];
    __syncthreads();
  }
  if (threadIdx.x == 0) partials2[blockIdx.x] = red[0];
}

__global__ void vnl_final(const Stats* __restrict__ st, const float* __restrict__ partials2,
                          int nb, float* __restrict__ out) {
  __shared__ double red[256];
  int tid = threadIdx.x;
  double s = 0.0;
  for (int i = tid; i < nb; i += 256) s += (double)partials2[i];
  red[tid] = s;
  __syncthreads();
  for (int off = 128; off > 0; off >>= 1) {
    if (tid < off) red[tid] += red[tid + off];
    __syncthreads();
  }
  if (tid == 0) {
    unsigned V = st->V, k = st->k;
    float res = 0.f;
    if (V > 0) {
      double tf = (double)__uint_as_float(st->prefix);
      double sum_keep = st->S_all - red[0] - (double)(k - st->cnt_lt) * tf;
      unsigned denom = V - k;
      if (denom < 1) denom = 1;
      res = (float)(sum_keep / (double)denom);
    }
    out[0] = res;
  }
}

}  // namespace

extern "C" void kernel_launch(void* const* d_in, const int* in_sizes, int n_in,
                              void* d_out, int out_size, void* d_ws, size_t ws_size,
                              hipStream_t stream) {
  const float* pred = (const float*)d_in[0];
  const float* gt = (const float*)d_in[1];
  const int* p1 = (const int*)d_in[2];
  const int* p2 = (const int*)d_in[3];
  const int* p3 = (const int*)d_in[4];
  int B = in_sizes[0] / HW;
  int G = in_sizes[2];
  int N = B * G;

  int blocksMain4 = (G + 255) / 256;
  int blocksMainN = (N + 255) / 256;

  char* ws = (char*)d_ws;
  size_t pk_bytes = (size_t)HW * 32;
  size_t ub_bytes = ((size_t)N * 4 + 255) & ~(size_t)255;
  size_t hm_bytes = (size_t)NB_HIST * 256 * 4;
  size_t pa_bytes = ((size_t)blocksMainN * 4 + 255) & ~(size_t)255;  // covers both paths
  size_t p2_bytes = (size_t)NB_HIST * 4;
  size_t need_fast = pk_bytes + ub_bytes + hm_bytes + pa_bytes + p2_bytes + sizeof(Stats) + 512;
  bool fast = (B == 4) && (ws_size >= need_fast);

  char* p = ws;
  float4* pk = nullptr;
  if (fast) { pk = (float4*)p; p += pk_bytes; }
  unsigned* ubits = (unsigned*)p; p += ub_bytes;
  unsigned* histmat = (unsigned*)p; p += hm_bytes;
  float* partials = (float*)p; p += pa_bytes;
  float* partials2 = (float*)p; p += p2_bytes;
  Stats* st = (Stats*)p;

  hipMemsetAsync(st, 0, sizeof(Stats), stream);

  int nPartials;
  if (fast) {
    vnl_pack<<<(HW + 255) / 256, 256, 0, stream>>>(pred, gt, pk);
    vnl_main4<<<blocksMain4, 256, 0, stream>>>(pk, p1, p2, p3, ubits, partials, G);
    nPartials = blocksMain4;
  } else {
    vnl_main<<<blocksMainN, 256, 0, stream>>>(pred, gt, p1, p2, p3, ubits, partials, G, N);
    nPartials = blocksMainN;
  }
  for (int pass = 0; pass < 4; ++pass) {
    vnl_hist<<<NB_HIST, 256, 0, stream>>>(ubits, histmat, st, N, pass);
    vnl_scan<<<1, 256, 0, stream>>>(histmat, st, pass, partials, nPartials);
  }
  vnl_sumlt<<<NB_HIST, 256, 0, stream>>>(ubits, st, partials2, N);
  vnl_final<<<1, 256, 0, stream>>>(st, partials2, NB_HIST, (float*)d_out);
}

// Round 4
// 100.083 us; speedup vs baseline: 6.7303x; 1.7917x over previous
//
#include <hip/hip_runtime.h>

#define HD __device__ __forceinline__

namespace {

constexpr int H = 1080, W = 1920, HW = H * W;
constexpr float FXc = 1000.0f, FYc = 1000.0f;
constexpr float D_COS = 0.867f, D_DIFF = 0.35f, D_Z = 0.05f, D_FARZ = 12.3f;
constexpr int NBH = 256;     // hist blocks (rows of histmat)
constexpr int NBINS = 16384; // 14-bit digit: sign+exp+5 mantissa bits
constexpr int NBS = 256;     // sumlt blocks

struct Stats {
  double S_all;
  unsigned V, k, cnt_lt, t_edge, t_mid, pad;
};

struct F3 { float x, y, z; };
HD F3 fsub(F3 a, F3 b) { return {a.x - b.x, a.y - b.y, a.z - b.z}; }
HD float fdot(F3 a, F3 b) { return a.x * b.x + a.y * b.y + a.z * b.z; }
HD F3 fcross(F3 a, F3 b) {
  return {a.y * b.z - a.z * b.y, a.z * b.x - a.x * b.z, a.x * b.y - a.y * b.x};
}

HD F3 mkpt2(float ux, float vy, float d) {
  float ad = fabsf(d);
  F3 p;
  p.x = ux * ad / FXc;
  p.y = vy * ad / FYc;
  p.z = d;
  return p;
}

HD F3 mkpt(int j, float d) {
  int v = j / W;
  int u = j - v * W;
  return mkpt2((float)(u - W / 2), (float)(v - H / 2), d);
}

// Core per-(group,batch) computation. Returns loss bits (0xFFFFFFFF if unmasked).
HD unsigned vnl_elem(F3 A, F3 Bp, F3 C, F3 P0, F3 P1, F3 P2, float* lv) {
  F3 e12 = fsub(Bp, A), e13 = fsub(C, A), e23 = fsub(C, Bp);
  F3 ev[3] = {e12, e13, e23};
  float nn[3] = {sqrtf(fdot(ev[0], ev[0])), sqrtf(fdot(ev[1], ev[1])),
                 sqrtf(fdot(ev[2], ev[2]))};
  int cnt = 0;
#pragma unroll
  for (int a = 0; a < 3; a++)
#pragma unroll
    for (int c = 0; c < 3; c++) {
      float ne = fdot(ev[a], ev[c]) / (nn[a] * nn[c] + 1e-8f);
      if (ne > D_COS || ne < -D_COS) cnt++;
    }
  bool mask_cos = cnt > 3;
  bool mask_pad = (A.z > D_Z) && (Bp.z > D_Z) && (C.z > D_Z);
  bool mask_far = (A.z < D_FARZ) && (Bp.z < D_FARZ) && (C.z < D_FARZ);
  bool mx = fabsf(e12.x) < D_DIFF || fabsf(e13.x) < D_DIFF || fabsf(e23.x) < D_DIFF;
  bool my = fabsf(e12.y) < D_DIFF || fabsf(e13.y) < D_DIFF || fabsf(e23.y) < D_DIFF;
  bool mz = fabsf(e12.z) < D_DIFF || fabsf(e13.z) < D_DIFF || fabsf(e23.z) < D_DIFF;
  bool masked = mask_pad && mask_far && !((mx && my && mz) || mask_cos);

  // reference's z_zero broadcast semantics:
  // if point c's z == 0, coordinate c of ALL points := 1e-4
  if (P0.z == 0.f) { P0.x = 1e-4f; P1.x = 1e-4f; P2.x = 1e-4f; }
  if (P1.z == 0.f) { P0.y = 1e-4f; P1.y = 1e-4f; P2.y = 1e-4f; }
  if (P2.z == 0.f) { P0.z = 1e-4f; P1.z = 1e-4f; P2.z = 1e-4f; }

  F3 ngt = fcross(e12, e13);
  float lg = sqrtf(fdot(ngt, ngt));
  lg += (lg == 0.f) ? 0.01f : 0.f;
  F3 q12 = fsub(P1, P0), q13 = fsub(P2, P0);
  F3 npr = fcross(q12, q13);
  float lp = sqrtf(fdot(npr, npr));
  lp += (lp == 0.f) ? 0.01f : 0.f;
  float l = fabsf(ngt.x / lg - npr.x / lp) + fabsf(ngt.y / lg - npr.y / lp) +
            fabsf(ngt.z / lg - npr.z / lp);
  if (masked) { *lv = l; return __float_as_uint(l); }
  *lv = 0.f;
  return 0xFFFFFFFFu;
}

union PxU {
  uint4 u;
  _Float16 h[8];
};

// ---- packed fast path (B == 4): [HW] x {gt[0..3], pred[0..3]} fp16 = 16B/pixel ----
__global__ void vnl_pack(const float* __restrict__ pred, const float* __restrict__ gt,
                         uint4* __restrict__ pk) {
  int j = blockIdx.x * blockDim.x + threadIdx.x;
  if (j >= HW) return;
  PxU x;
  x.h[0] = (_Float16)gt[j];
  x.h[1] = (_Float16)gt[HW + j];
  x.h[2] = (_Float16)gt[2 * HW + j];
  x.h[3] = (_Float16)gt[3 * HW + j];
  x.h[4] = (_Float16)pred[j];
  x.h[5] = (_Float16)pred[HW + j];
  x.h[6] = (_Float16)pred[2 * HW + j];
  x.h[7] = (_Float16)pred[3 * HW + j];
  pk[j] = x.u;
}

__global__ void vnl_main4(const uint4* __restrict__ pk, const int* __restrict__ p1,
                          const int* __restrict__ p2, const int* __restrict__ p3,
                          unsigned* __restrict__ ubits, float* __restrict__ partials,
                          int G) {
  int g = blockIdx.x * blockDim.x + threadIdx.x;
  float lsum = 0.f;
  if (g < G) {
    int j[3] = {p1[g], p2[g], p3[g]};
    float gd[3][4], pd[3][4];
    float ux[3], vy[3];
#pragma unroll
    for (int c = 0; c < 3; ++c) {
      int jj = j[c];
      PxU x;
      x.u = pk[jj];
#pragma unroll
      for (int b = 0; b < 4; ++b) {
        gd[c][b] = (float)x.h[b];
        pd[c][b] = (float)x.h[4 + b];
      }
      int vrow = jj / W;
      int ucol = jj - vrow * W;
      ux[c] = (float)(ucol - W / 2);
      vy[c] = (float)(vrow - H / 2);
    }
#pragma unroll
    for (int b = 0; b < 4; ++b) {
      F3 A = mkpt2(ux[0], vy[0], gd[0][b]);
      F3 Bp = mkpt2(ux[1], vy[1], gd[1][b]);
      F3 C = mkpt2(ux[2], vy[2], gd[2][b]);
      F3 P0 = mkpt2(ux[0], vy[0], pd[0][b]);
      F3 P1 = mkpt2(ux[1], vy[1], pd[1][b]);
      F3 P2 = mkpt2(ux[2], vy[2], pd[2][b]);
      float lv;
      unsigned bits = vnl_elem(A, Bp, C, P0, P1, P2, &lv);
      lsum += lv;
      ubits[b * G + g] = bits;
    }
  }
  __shared__ float red[256];
  red[threadIdx.x] = lsum;
  __syncthreads();
  for (int off = 128; off > 0; off >>= 1) {
    if (threadIdx.x < (unsigned)off) red[threadIdx.x] += red[threadIdx.x + off];
    __syncthreads();
  }
  if (threadIdx.x == 0) partials[blockIdx.x] = red[0];
}

// ---- fallback scalar path (any B) ----
__global__ void vnl_main(const float* __restrict__ pred, const float* __restrict__ gt,
                         const int* __restrict__ p1, const int* __restrict__ p2,
                         const int* __restrict__ p3, unsigned* __restrict__ ubits,
                         float* __restrict__ partials, int G, int N) {
  int i = blockIdx.x * blockDim.x + threadIdx.x;
  float lv = 0.f;
  if (i < N) {
    int b = i / G;
    int g = i - b * G;
    int j1 = p1[g], j2 = p2[g], j3 = p3[g];
    const float* gb = gt + (size_t)b * HW;
    const float* pb = pred + (size_t)b * HW;
    unsigned bits = vnl_elem(mkpt(j1, gb[j1]), mkpt(j2, gb[j2]), mkpt(j3, gb[j3]),
                             mkpt(j1, pb[j1]), mkpt(j2, pb[j2]), mkpt(j3, pb[j3]), &lv);
    ubits[i] = bits;
  }
  __shared__ float red[256];
  red[threadIdx.x] = lv;
  __syncthreads();
  for (int off = 128; off > 0; off >>= 1) {
    if (threadIdx.x < (unsigned)off) red[threadIdx.x] += red[threadIdx.x + off];
    __syncthreads();
  }
  if (threadIdx.x == 0) partials[blockIdx.x] = red[0];
}

// ---- single-pass 14-bit histogram select ----
// digit = bits >> 18 (sign + 8 exp + 5 mantissa). Sentinels (unmasked) skipped.
__global__ void vnl_hist(const unsigned* __restrict__ ubits, unsigned* __restrict__ histmat,
                         int N) {
  __shared__ unsigned h[NBINS];
  int tid = threadIdx.x;
  for (int i = tid; i < NBINS; i += 256) h[i] = 0;
  __syncthreads();
  for (int i = blockIdx.x * 256 + tid; i < N; i += NBH * 256) {
    unsigned v = ubits[i];
    if (v != 0xFFFFFFFFu) atomicAdd(&h[v >> 18], 1u);
  }
  __syncthreads();
  for (int i = tid; i < NBINS; i += 256)
    histmat[(size_t)blockIdx.x * NBINS + i] = h[i];
}

// 256 blocks x 256 threads: column-reduce histmat[NBH][NBINS] -> hist[NBINS]
__global__ void vnl_colred(const unsigned* __restrict__ histmat, unsigned* __restrict__ hist) {
  int tid = threadIdx.x;
  int bin = blockIdx.x * 64 + (tid & 63);
  int r0 = (tid >> 6) * (NBH / 4);
  unsigned s = 0;
  for (int r = r0; r < r0 + NBH / 4; ++r) s += histmat[(size_t)r * NBINS + bin];
  __shared__ unsigned red[256];
  red[tid] = s;
  __syncthreads();
  if (tid < 128) red[tid] += red[tid + 128];
  __syncthreads();
  if (tid < 64) hist[blockIdx.x * 64 + tid] = red[tid] + red[tid + 64];
}

// single block, 1024 threads: scan 16384 bins, find k-th bin, reduce S_all partials.
__global__ void vnl_scan(const unsigned* __restrict__ hist, Stats* st,
                         const float* __restrict__ partials, int nPartials) {
  __shared__ unsigned tsum[1024];
  __shared__ double sred[1024];
  int tid = threadIdx.x;
  unsigned s = 0;
#pragma unroll
  for (int j = 0; j < 16; ++j) s += hist[tid * 16 + j];
  tsum[tid] = s;
  double ps = 0.0;
  for (int i = tid; i < nPartials; i += 1024) ps += (double)partials[i];
  sred[tid] = ps;
  __syncthreads();
  for (int off = 1; off < 1024; off <<= 1) {
    unsigned v = (tid >= off) ? tsum[tid - off] : 0u;
    __syncthreads();
    tsum[tid] += v;
    __syncthreads();
  }
  for (int off = 512; off > 0; off >>= 1) {
    if (tid < off) sred[tid] += sred[tid + off];
    __syncthreads();
  }
  unsigned V = tsum[1023];
  unsigned k = V >> 2;
  if (tid == 0) {
    st->S_all = sred[0];
    st->V = V;
    st->k = k;
    if (k == 0) { st->cnt_lt = 0; st->t_edge = 0; st->t_mid = 0; }
  }
  unsigned base = tsum[tid] - s;
  if (k >= 1 && tsum[tid] >= k && base < k) {  // exactly one thread
    unsigned run = base;
#pragma unroll
    for (int j = 0; j < 16; ++j) {
      unsigned c = hist[tid * 16 + j];
      if (run + c >= k) {
        unsigned bin = (unsigned)(tid * 16 + j);
        st->cnt_lt = run;
        st->t_edge = bin << 18;
        st->t_mid = (bin << 18) | 0x20000u;
        break;
      }
      run += c;
    }
  }
}

__global__ void vnl_sumlt(const unsigned* __restrict__ ubits, const Stats* __restrict__ st,
                          float* __restrict__ partials2, int N) {
  unsigned t = st->t_edge;
  float lv = 0.f;
  for (int i = blockIdx.x * blockDim.x + threadIdx.x; i < N; i += NBS * 256) {
    unsigned v = ubits[i];
    if (v < t) lv += __uint_as_float(v);
  }
  __shared__ float red[256];
  red[threadIdx.x] = lv;
  __syncthreads();
  for (int off = 128; off > 0; off >>= 1) {
    if (threadIdx.x < (unsigned)off) red[threadIdx.x] += red[threadIdx.x + off];
    __syncthreads();
  }
  if (threadIdx.x == 0) partials2[blockIdx.x] = red[0];
}

__global__ void vnl_final(const Stats* __restrict__ st, const float* __restrict__ partials2,
                          float* __restrict__ out) {
  __shared__ double red[256];
  int tid = threadIdx.x;
  red[tid] = (double)partials2[tid];
  __syncthreads();
  for (int off = 128; off > 0; off >>= 1) {
    if (tid < off) red[tid] += red[tid + off];
    __syncthreads();
  }
  if (tid == 0) {
    unsigned V = st->V, k = st->k;
    float res = 0.f;
    if (V > 0) {
      double tmid = (double)__uint_as_float(st->t_mid);
      double sum_keep = st->S_all - red[0] - (double)(k - st->cnt_lt) * tmid;
      unsigned denom = V - k;
      if (denom < 1) denom = 1;
      res = (float)(sum_keep / (double)denom);
    }
    out[0] = res;
  }
}

}  // namespace

extern "C" void kernel_launch(void* const* d_in, const int* in_sizes, int n_in,
                              void* d_out, int out_size, void* d_ws, size_t ws_size,
                              hipStream_t stream) {
  const float* pred = (const float*)d_in[0];
  const float* gt = (const float*)d_in[1];
  const int* p1 = (const int*)d_in[2];
  const int* p2 = (const int*)d_in[3];
  const int* p3 = (const int*)d_in[4];
  int B = in_sizes[0] / HW;
  int G = in_sizes[2];
  int N = B * G;

  int blocksMain4 = (G + 255) / 256;
  int blocksMainN = (N + 255) / 256;

  char* ws = (char*)d_ws;
  size_t pk_bytes = (size_t)HW * 16;
  size_t ub_bytes = ((size_t)N * 4 + 255) & ~(size_t)255;
  size_t hm_bytes = (size_t)NBH * NBINS * 4;
  size_t h_bytes = (size_t)NBINS * 4;
  size_t pa_bytes = ((size_t)blocksMainN * 4 + 255) & ~(size_t)255;  // covers both paths
  size_t p2_bytes = (size_t)NBS * 4;
  size_t need_fast =
      pk_bytes + ub_bytes + hm_bytes + h_bytes + pa_bytes + p2_bytes + sizeof(Stats) + 512;
  bool fast = (B == 4) && (ws_size >= need_fast);

  char* p = ws;
  uint4* pk = nullptr;
  if (fast) { pk = (uint4*)p; p += pk_bytes; }
  unsigned* ubits = (unsigned*)p; p += ub_bytes;
  unsigned* histmat = (unsigned*)p; p += hm_bytes;
  unsigned* hist = (unsigned*)p; p += h_bytes;
  float* partials = (float*)p; p += pa_bytes;
  float* partials2 = (float*)p; p += p2_bytes;
  Stats* st = (Stats*)p;

  int nPartials;
  if (fast) {
    vnl_pack<<<(HW + 255) / 256, 256, 0, stream>>>(pred, gt, pk);
    vnl_main4<<<blocksMain4, 256, 0, stream>>>(pk, p1, p2, p3, ubits, partials, G);
    nPartials = blocksMain4;
  } else {
    vnl_main<<<blocksMainN, 256, 0, stream>>>(pred, gt, p1, p2, p3, ubits, partials, G, N);
    nPartials = blocksMainN;
  }
  vnl_hist<<<NBH, 256, 0, stream>>>(ubits, histmat, N);
  vnl_colred<<<NBINS / 64, 256, 0, stream>>>(histmat, hist);
  vnl_scan<<<1, 1024, 0, stream>>>(hist, st, partials, nPartials);
  vnl_sumlt<<<NBS, 256, 0, stream>>>(ubits, st, partials2, N);
  vnl_final<<<1, 256, 0, stream>>>(st, partials2, (float*)d_out);
}

// Round 5
// 93.820 us; speedup vs baseline: 7.1795x; 1.0667x over previous
//
#include <hip/hip_runtime.h>

#define HD __device__ __forceinline__

namespace {

constexpr int H = 1080, W = 1920, HW = H * W;
constexpr float FXc = 1000.0f, FYc = 1000.0f;
constexpr float D_COS = 0.867f, D_DIFF = 0.35f, D_Z = 0.05f, D_FARZ = 12.3f;
constexpr int NBH = 256;    // hist blocks
constexpr int NBINS = 8192; // bits>>18 for non-negative floats: 0 exp(8) man(5)

struct F3 { float x, y, z; };
HD F3 fsub(F3 a, F3 b) { return {a.x - b.x, a.y - b.y, a.z - b.z}; }
HD float fdot(F3 a, F3 b) { return a.x * b.x + a.y * b.y + a.z * b.z; }
HD F3 fcross(F3 a, F3 b) {
  return {a.y * b.z - a.z * b.y, a.z * b.x - a.x * b.z, a.x * b.y - a.y * b.x};
}

HD F3 mkpt2(float ux, float vy, float d) {
  float ad = fabsf(d);
  F3 p;
  p.x = ux * ad / FXc;
  p.y = vy * ad / FYc;
  p.z = d;
  return p;
}

HD F3 mkpt(int j, float d) {
  int v = j / W;
  int u = j - v * W;
  return mkpt2((float)(u - W / 2), (float)(v - H / 2), d);
}

// Core per-(group,batch) computation. Returns loss bits (0xFFFFFFFF if unmasked).
HD unsigned vnl_elem(F3 A, F3 Bp, F3 C, F3 P0, F3 P1, F3 P2) {
  F3 e12 = fsub(Bp, A), e13 = fsub(C, A), e23 = fsub(C, Bp);
  F3 ev[3] = {e12, e13, e23};
  float nn[3] = {sqrtf(fdot(ev[0], ev[0])), sqrtf(fdot(ev[1], ev[1])),
                 sqrtf(fdot(ev[2], ev[2]))};
  int cnt = 0;
#pragma unroll
  for (int a = 0; a < 3; a++)
#pragma unroll
    for (int c = 0; c < 3; c++) {
      float ne = fdot(ev[a], ev[c]) / (nn[a] * nn[c] + 1e-8f);
      if (ne > D_COS || ne < -D_COS) cnt++;
    }
  bool mask_cos = cnt > 3;
  bool mask_pad = (A.z > D_Z) && (Bp.z > D_Z) && (C.z > D_Z);
  bool mask_far = (A.z < D_FARZ) && (Bp.z < D_FARZ) && (C.z < D_FARZ);
  bool mx = fabsf(e12.x) < D_DIFF || fabsf(e13.x) < D_DIFF || fabsf(e23.x) < D_DIFF;
  bool my = fabsf(e12.y) < D_DIFF || fabsf(e13.y) < D_DIFF || fabsf(e23.y) < D_DIFF;
  bool mz = fabsf(e12.z) < D_DIFF || fabsf(e13.z) < D_DIFF || fabsf(e23.z) < D_DIFF;
  bool masked = mask_pad && mask_far && !((mx && my && mz) || mask_cos);

  // reference's z_zero broadcast semantics:
  // if point c's z == 0, coordinate c of ALL points := 1e-4
  if (P0.z == 0.f) { P0.x = 1e-4f; P1.x = 1e-4f; P2.x = 1e-4f; }
  if (P1.z == 0.f) { P0.y = 1e-4f; P1.y = 1e-4f; P2.y = 1e-4f; }
  if (P2.z == 0.f) { P0.z = 1e-4f; P1.z = 1e-4f; P2.z = 1e-4f; }

  F3 ngt = fcross(e12, e13);
  float lg = sqrtf(fdot(ngt, ngt));
  lg += (lg == 0.f) ? 0.01f : 0.f;
  F3 q12 = fsub(P1, P0), q13 = fsub(P2, P0);
  F3 npr = fcross(q12, q13);
  float lp = sqrtf(fdot(npr, npr));
  lp += (lp == 0.f) ? 0.01f : 0.f;
  float l = fabsf(ngt.x / lg - npr.x / lp) + fabsf(ngt.y / lg - npr.y / lp) +
            fabsf(ngt.z / lg - npr.z / lp);
  return masked ? __float_as_uint(l) : 0xFFFFFFFFu;
}

union PxU {
  uint4 u;
  _Float16 h[8];
};

// ---- packed fast path (B == 4): [HW] x {gt[0..3], pred[0..3]} fp16 = 16B/pixel ----
__global__ void vnl_pack(const float* __restrict__ pred, const float* __restrict__ gt,
                         uint4* __restrict__ pk) {
  int j = blockIdx.x * blockDim.x + threadIdx.x;
  if (j >= HW) return;
  PxU x;
  x.h[0] = (_Float16)gt[j];
  x.h[1] = (_Float16)gt[HW + j];
  x.h[2] = (_Float16)gt[2 * HW + j];
  x.h[3] = (_Float16)gt[3 * HW + j];
  x.h[4] = (_Float16)pred[j];
  x.h[5] = (_Float16)pred[HW + j];
  x.h[6] = (_Float16)pred[2 * HW + j];
  x.h[7] = (_Float16)pred[3 * HW + j];
  pk[j] = x.u;
}

// 2 groups per thread for deeper memory-level parallelism (6 gathers in flight).
__global__ void vnl_main4(const uint4* __restrict__ pk, const int* __restrict__ p1,
                          const int* __restrict__ p2, const int* __restrict__ p3,
                          unsigned* __restrict__ ubits, int G, int Gh) {
  int t = blockIdx.x * blockDim.x + threadIdx.x;
  if (t >= Gh) return;
  int gs[2] = {t, t + Gh};
  int ng = (gs[1] < G) ? 2 : 1;
  int j[2][3];
  PxU px[2][3];
#pragma unroll
  for (int q = 0; q < 2; ++q) {
    if (q < ng) {
      int g = gs[q];
      j[q][0] = p1[g];
      j[q][1] = p2[g];
      j[q][2] = p3[g];
    }
  }
#pragma unroll
  for (int q = 0; q < 2; ++q)
#pragma unroll
    for (int c = 0; c < 3; ++c)
      if (q < ng) px[q][c].u = pk[j[q][c]];

#pragma unroll
  for (int q = 0; q < 2; ++q) {
    if (q >= ng) break;
    float ux[3], vy[3];
#pragma unroll
    for (int c = 0; c < 3; ++c) {
      int jj = j[q][c];
      int vrow = jj / W;
      int ucol = jj - vrow * W;
      ux[c] = (float)(ucol - W / 2);
      vy[c] = (float)(vrow - H / 2);
    }
#pragma unroll
    for (int b = 0; b < 4; ++b) {
      F3 A = mkpt2(ux[0], vy[0], (float)px[q][0].h[b]);
      F3 Bp = mkpt2(ux[1], vy[1], (float)px[q][1].h[b]);
      F3 C = mkpt2(ux[2], vy[2], (float)px[q][2].h[b]);
      F3 P0 = mkpt2(ux[0], vy[0], (float)px[q][0].h[4 + b]);
      F3 P1 = mkpt2(ux[1], vy[1], (float)px[q][1].h[4 + b]);
      F3 P2 = mkpt2(ux[2], vy[2], (float)px[q][2].h[4 + b]);
      ubits[b * G + gs[q]] = vnl_elem(A, Bp, C, P0, P1, P2);
    }
  }
}

// ---- fallback scalar path (any B) ----
__global__ void vnl_main(const float* __restrict__ pred, const float* __restrict__ gt,
                         const int* __restrict__ p1, const int* __restrict__ p2,
                         const int* __restrict__ p3, unsigned* __restrict__ ubits,
                         int G, int N) {
  int i = blockIdx.x * blockDim.x + threadIdx.x;
  if (i >= N) return;
  int b = i / G;
  int g = i - b * G;
  int j1 = p1[g], j2 = p2[g], j3 = p3[g];
  const float* gb = gt + (size_t)b * HW;
  const float* pb = pred + (size_t)b * HW;
  ubits[i] = vnl_elem(mkpt(j1, gb[j1]), mkpt(j2, gb[j2]), mkpt(j3, gb[j3]),
                      mkpt(j1, pb[j1]), mkpt(j2, pb[j2]), mkpt(j3, pb[j3]));
}

// ---- per-bin {count,sum} histogram (8192 bins = bits>>18 for non-neg floats) ----
__global__ void vnl_hist(const unsigned* __restrict__ ubits, unsigned* __restrict__ hc,
                         float* __restrict__ hs, int N) {
  __shared__ unsigned cnt[NBINS];
  __shared__ float sum[NBINS];
  int tid = threadIdx.x;
  for (int i = tid; i < NBINS; i += 256) { cnt[i] = 0; sum[i] = 0.f; }
  __syncthreads();
  for (int i = blockIdx.x * 256 + tid; i < N; i += NBH * 256) {
    unsigned v = ubits[i];
    if (v != 0xFFFFFFFFu) {
      atomicAdd(&cnt[v >> 18], 1u);
      atomicAdd(&sum[v >> 18], __uint_as_float(v));
    }
  }
  __syncthreads();
  for (int i = tid; i < NBINS; i += 256) {
    unsigned c = cnt[i];
    if (c) {
      atomicAdd(&hc[i], c);
      atomicAdd(&hs[i], sum[i]);
    }
  }
}

// single block, 1024 threads: scan 8192 bins, compute trimmed mean, write out.
__global__ void vnl_scanfinal(const unsigned* __restrict__ hc, const float* __restrict__ hs,
                              float* __restrict__ out) {
  __shared__ unsigned tsum[1024];
  __shared__ double dsum[1024];
  int tid = threadIdx.x;
  unsigned c8[8];
  float s8[8];
  unsigned s = 0;
  double d = 0.0;
#pragma unroll
  for (int jj = 0; jj < 8; ++jj) {
    c8[jj] = hc[tid * 8 + jj];
    s8[jj] = hs[tid * 8 + jj];
    s += c8[jj];
    d += (double)s8[jj];
  }
  tsum[tid] = s;
  dsum[tid] = d;
  __syncthreads();
  for (int off = 1; off < 1024; off <<= 1) {
    unsigned v = (tid >= off) ? tsum[tid - off] : 0u;
    double w = (tid >= off) ? dsum[tid - off] : 0.0;
    __syncthreads();
    tsum[tid] += v;
    dsum[tid] += w;
    __syncthreads();
  }
  unsigned V = tsum[1023];
  double S_all = dsum[1023];
  unsigned k = V >> 2;
  if (V == 0) {
    if (tid == 0) out[0] = 0.f;
    return;
  }
  if (k == 0) {
    if (tid == 0) out[0] = (float)(S_all / (double)V);
    return;
  }
  unsigned base = tsum[tid] - s;
  if (tsum[tid] >= k && base < k) {  // exactly one winner
    unsigned run = base;
    double acc = dsum[tid] - d;  // sum of all bins in earlier threads
#pragma unroll
    for (int jj = 0; jj < 8; ++jj) {
      unsigned c = c8[jj];
      if (run + c >= k) {
        unsigned bin = (unsigned)(tid * 8 + jj);
        double tmid = (double)__uint_as_float((bin << 18) | 0x20000u);
        double sum_keep = S_all - acc - (double)(k - run) * tmid;
        unsigned denom = V - k;
        if (denom < 1) denom = 1;
        out[0] = (float)(sum_keep / (double)denom);
        break;
      }
      run += c;
      acc += (double)s8[jj];
    }
  }
}

}  // namespace

extern "C" void kernel_launch(void* const* d_in, const int* in_sizes, int n_in,
                              void* d_out, int out_size, void* d_ws, size_t ws_size,
                              hipStream_t stream) {
  const float* pred = (const float*)d_in[0];
  const float* gt = (const float*)d_in[1];
  const int* p1 = (const int*)d_in[2];
  const int* p2 = (const int*)d_in[3];
  const int* p3 = (const int*)d_in[4];
  int B = in_sizes[0] / HW;
  int G = in_sizes[2];
  int N = B * G;

  char* ws = (char*)d_ws;
  size_t pk_bytes = (size_t)HW * 16;
  size_t ub_bytes = ((size_t)N * 4 + 255) & ~(size_t)255;
  size_t hist_bytes = (size_t)NBINS * 4;
  size_t need_fast = pk_bytes + ub_bytes + 2 * hist_bytes + 512;
  bool fast = (B == 4) && (ws_size >= need_fast);

  char* p = ws;
  uint4* pk = nullptr;
  if (fast) { pk = (uint4*)p; p += pk_bytes; }
  unsigned* ubits = (unsigned*)p; p += ub_bytes;
  unsigned* hc = (unsigned*)p; p += hist_bytes;
  float* hs = (float*)p;

  hipMemsetAsync(hc, 0, 2 * hist_bytes, stream);

  if (fast) {
    int Gh = (G + 1) / 2;
    vnl_pack<<<(HW + 255) / 256, 256, 0, stream>>>(pred, gt, pk);
    vnl_main4<<<(Gh + 255) / 256, 256, 0, stream>>>(pk, p1, p2, p3, ubits, G, Gh);
  } else {
    vnl_main<<<(N + 255) / 256, 256, 0, stream>>>(pred, gt, p1, p2, p3, ubits, G, N);
  }
  vnl_hist<<<NBH, 256, 0, stream>>>(ubits, hc, hs, N);
  vnl_scanfinal<<<1, 1024, 0, stream>>>(hc, hs, (float*)d_out);
}

// Round 6
// 74.665 us; speedup vs baseline: 9.0214x; 1.2565x over previous
//
#include <hip/hip_runtime.h>

#define HD __device__ __forceinline__

namespace {

constexpr int H = 1080, W = 1920, HW = H * W;
constexpr float FXc = 1000.0f, FYc = 1000.0f;
constexpr float D_COS = 0.867f, D_DIFF = 0.35f, D_Z = 0.05f, D_FARZ = 12.3f;
constexpr int NBH = 256;    // hist blocks
constexpr int NBINS = 8192; // bits>>18 for non-negative floats: 0 exp(8) man(5)

struct F3 { float x, y, z; };
HD F3 fsub(F3 a, F3 b) { return {a.x - b.x, a.y - b.y, a.z - b.z}; }
HD float fdot(F3 a, F3 b) { return a.x * b.x + a.y * b.y + a.z * b.z; }
HD F3 fcross(F3 a, F3 b) {
  return {a.y * b.z - a.z * b.y, a.z * b.x - a.x * b.z, a.x * b.y - a.y * b.x};
}

HD F3 mkpt2(float ux, float vy, float d) {
  float ad = fabsf(d);
  F3 p;
  p.x = ux * ad / FXc;
  p.y = vy * ad / FYc;
  p.z = d;
  return p;
}

HD F3 mkpt(int j, float d) {
  int v = j / W;
  int u = j - v * W;
  return mkpt2((float)(u - W / 2), (float)(v - H / 2), d);
}

// Core per-(group,batch) computation. Returns loss bits (0xFFFFFFFF if unmasked).
// Division-light: cosine test via |dot| > D_COS*(na*nb+eps) (denominator > 0),
// normals normalized with 2 reciprocals instead of 6 divisions.
HD unsigned vnl_elem(F3 A, F3 Bp, F3 C, F3 P0, F3 P1, F3 P2) {
  F3 e12 = fsub(Bp, A), e13 = fsub(C, A), e23 = fsub(C, Bp);
  F3 ev[3] = {e12, e13, e23};
  float nn[3] = {sqrtf(fdot(ev[0], ev[0])), sqrtf(fdot(ev[1], ev[1])),
                 sqrtf(fdot(ev[2], ev[2]))};
  int cnt = 0;
#pragma unroll
  for (int a = 0; a < 3; a++)
#pragma unroll
    for (int c = 0; c < 3; c++) {
      float thr = D_COS * (nn[a] * nn[c] + 1e-8f);
      if (fabsf(fdot(ev[a], ev[c])) > thr) cnt++;
    }
  bool mask_cos = cnt > 3;
  bool mask_pad = (A.z > D_Z) && (Bp.z > D_Z) && (C.z > D_Z);
  bool mask_far = (A.z < D_FARZ) && (Bp.z < D_FARZ) && (C.z < D_FARZ);
  bool mx = fabsf(e12.x) < D_DIFF || fabsf(e13.x) < D_DIFF || fabsf(e23.x) < D_DIFF;
  bool my = fabsf(e12.y) < D_DIFF || fabsf(e13.y) < D_DIFF || fabsf(e23.y) < D_DIFF;
  bool mz = fabsf(e12.z) < D_DIFF || fabsf(e13.z) < D_DIFF || fabsf(e23.z) < D_DIFF;
  bool masked = mask_pad && mask_far && !((mx && my && mz) || mask_cos);

  // reference's z_zero broadcast semantics:
  // if point c's z == 0, coordinate c of ALL points := 1e-4
  if (P0.z == 0.f) { P0.x = 1e-4f; P1.x = 1e-4f; P2.x = 1e-4f; }
  if (P1.z == 0.f) { P0.y = 1e-4f; P1.y = 1e-4f; P2.y = 1e-4f; }
  if (P2.z == 0.f) { P0.z = 1e-4f; P1.z = 1e-4f; P2.z = 1e-4f; }

  F3 ngt = fcross(e12, e13);
  float lg = sqrtf(fdot(ngt, ngt));
  lg += (lg == 0.f) ? 0.01f : 0.f;
  F3 q12 = fsub(P1, P0), q13 = fsub(P2, P0);
  F3 npr = fcross(q12, q13);
  float lp = sqrtf(fdot(npr, npr));
  lp += (lp == 0.f) ? 0.01f : 0.f;
  float ig = 1.0f / lg, ip = 1.0f / lp;
  float l = fabsf(ngt.x * ig - npr.x * ip) + fabsf(ngt.y * ig - npr.y * ip) +
            fabsf(ngt.z * ig - npr.z * ip);
  return masked ? __float_as_uint(l) : 0xFFFFFFFFu;
}

union PxU {
  uint4 u;
  _Float16 h[8];
};

// ---- packed fast path (B == 4): [HW] x {gt[0..3], pred[0..3]} fp16 = 16B/pixel ----
__global__ void vnl_pack(const float* __restrict__ pred, const float* __restrict__ gt,
                         uint4* __restrict__ pk) {
  int j = blockIdx.x * blockDim.x + threadIdx.x;
  if (j >= HW) return;
  PxU x;
  x.h[0] = (_Float16)gt[j];
  x.h[1] = (_Float16)gt[HW + j];
  x.h[2] = (_Float16)gt[2 * HW + j];
  x.h[3] = (_Float16)gt[3 * HW + j];
  x.h[4] = (_Float16)pred[j];
  x.h[5] = (_Float16)pred[HW + j];
  x.h[6] = (_Float16)pred[2 * HW + j];
  x.h[7] = (_Float16)pred[3 * HW + j];
  pk[j] = x.u;
}

// 1 group/thread, block=128 for maximal resident-wave concurrency.
__global__ void __launch_bounds__(128) vnl_main4(
    const uint4* __restrict__ pk, const int* __restrict__ p1,
    const int* __restrict__ p2, const int* __restrict__ p3,
    unsigned* __restrict__ ubits, int G) {
  int g = blockIdx.x * blockDim.x + threadIdx.x;
  if (g >= G) return;
  int j0 = p1[g], j1 = p2[g], j2 = p3[g];
  PxU x0, x1, x2;
  x0.u = pk[j0];
  x1.u = pk[j1];
  x2.u = pk[j2];
  int vr0 = j0 / W, vr1 = j1 / W, vr2 = j2 / W;
  float ux0 = (float)(j0 - vr0 * W - W / 2), vy0 = (float)(vr0 - H / 2);
  float ux1 = (float)(j1 - vr1 * W - W / 2), vy1 = (float)(vr1 - H / 2);
  float ux2 = (float)(j2 - vr2 * W - W / 2), vy2 = (float)(vr2 - H / 2);
#pragma unroll
  for (int b = 0; b < 4; ++b) {
    F3 A = mkpt2(ux0, vy0, (float)x0.h[b]);
    F3 Bp = mkpt2(ux1, vy1, (float)x1.h[b]);
    F3 C = mkpt2(ux2, vy2, (float)x2.h[b]);
    F3 P0 = mkpt2(ux0, vy0, (float)x0.h[4 + b]);
    F3 P1 = mkpt2(ux1, vy1, (float)x1.h[4 + b]);
    F3 P2 = mkpt2(ux2, vy2, (float)x2.h[4 + b]);
    ubits[b * G + g] = vnl_elem(A, Bp, C, P0, P1, P2);
  }
}

// ---- fallback scalar path (any B) ----
__global__ void vnl_main(const float* __restrict__ pred, const float* __restrict__ gt,
                         const int* __restrict__ p1, const int* __restrict__ p2,
                         const int* __restrict__ p3, unsigned* __restrict__ ubits,
                         int G, int N) {
  int i = blockIdx.x * blockDim.x + threadIdx.x;
  if (i >= N) return;
  int b = i / G;
  int g = i - b * G;
  int j1 = p1[g], j2 = p2[g], j3 = p3[g];
  const float* gb = gt + (size_t)b * HW;
  const float* pb = pred + (size_t)b * HW;
  ubits[i] = vnl_elem(mkpt(j1, gb[j1]), mkpt(j2, gb[j2]), mkpt(j3, gb[j3]),
                      mkpt(j1, pb[j1]), mkpt(j2, pb[j2]), mkpt(j3, pb[j3]));
}

// ---- per-bin {count,sum} histogram (8192 bins = bits>>18 for non-neg floats) ----
__global__ void vnl_hist(const unsigned* __restrict__ ubits, unsigned* __restrict__ hc,
                         float* __restrict__ hs, int N) {
  __shared__ unsigned cnt[NBINS];
  __shared__ float sum[NBINS];
  int tid = threadIdx.x;
  for (int i = tid; i < NBINS; i += 256) { cnt[i] = 0; sum[i] = 0.f; }
  __syncthreads();
  for (int i = blockIdx.x * 256 + tid; i < N; i += NBH * 256) {
    unsigned v = ubits[i];
    if (v != 0xFFFFFFFFu) {
      atomicAdd(&cnt[v >> 18], 1u);
      atomicAdd(&sum[v >> 18], __uint_as_float(v));
    }
  }
  __syncthreads();
  for (int i = tid; i < NBINS; i += 256) {
    unsigned c = cnt[i];
    if (c) {
      atomicAdd(&hc[i], c);
      atomicAdd(&hs[i], sum[i]);
    }
  }
}

// single block, 1024 threads: scan 8192 bins, compute trimmed mean, write out.
__global__ void vnl_scanfinal(const unsigned* __restrict__ hc, const float* __restrict__ hs,
                              float* __restrict__ out) {
  __shared__ unsigned tsum[1024];
  __shared__ double dsum[1024];
  int tid = threadIdx.x;
  unsigned c8[8];
  float s8[8];
  unsigned s = 0;
  double d = 0.0;
#pragma unroll
  for (int jj = 0; jj < 8; ++jj) {
    c8[jj] = hc[tid * 8 + jj];
    s8[jj] = hs[tid * 8 + jj];
    s += c8[jj];
    d += (double)s8[jj];
  }
  tsum[tid] = s;
  dsum[tid] = d;
  __syncthreads();
  for (int off = 1; off < 1024; off <<= 1) {
    unsigned v = (tid >= off) ? tsum[tid - off] : 0u;
    double w = (tid >= off) ? dsum[tid - off] : 0.0;
    __syncthreads();
    tsum[tid] += v;
    dsum[tid] += w;
    __syncthreads();
  }
  unsigned V = tsum[1023];
  double S_all = dsum[1023];
  unsigned k = V >> 2;
  if (V == 0) {
    if (tid == 0) out[0] = 0.f;
    return;
  }
  if (k == 0) {
    if (tid == 0) out[0] = (float)(S_all / (double)V);
    return;
  }
  unsigned base = tsum[tid] - s;
  if (tsum[tid] >= k && base < k) {  // exactly one winner
    unsigned run = base;
    double acc = dsum[tid] - d;  // sum of all bins in earlier threads
#pragma unroll
    for (int jj = 0; jj < 8; ++jj) {
      unsigned c = c8[jj];
      if (run + c >= k) {
        unsigned bin = (unsigned)(tid * 8 + jj);
        double tmid = (double)__uint_as_float((bin << 18) | 0x20000u);
        double sum_keep = S_all - acc - (double)(k - run) * tmid;
        unsigned denom = V - k;
        if (denom < 1) denom = 1;
        out[0] = (float)(sum_keep / (double)denom);
        break;
      }
      run += c;
      acc += (double)s8[jj];
    }
  }
}

}  // namespace

extern "C" void kernel_launch(void* const* d_in, const int* in_sizes, int n_in,
                              void* d_out, int out_size, void* d_ws, size_t ws_size,
                              hipStream_t stream) {
  const float* pred = (const float*)d_in[0];
  const float* gt = (const float*)d_in[1];
  const int* p1 = (const int*)d_in[2];
  const int* p2 = (const int*)d_in[3];
  const int* p3 = (const int*)d_in[4];
  int B = in_sizes[0] / HW;
  int G = in_sizes[2];
  int N = B * G;

  char* ws = (char*)d_ws;
  size_t pk_bytes = (size_t)HW * 16;
  size_t ub_bytes = ((size_t)N * 4 + 255) & ~(size_t)255;
  size_t hist_bytes = (size_t)NBINS * 4;
  size_t need_fast = pk_bytes + ub_bytes + 2 * hist_bytes + 512;
  bool fast = (B == 4) && (ws_size >= need_fast);

  char* p = ws;
  uint4* pk = nullptr;
  if (fast) { pk = (uint4*)p; p += pk_bytes; }
  unsigned* ubits = (unsigned*)p; p += ub_bytes;
  unsigned* hc = (unsigned*)p; p += hist_bytes;
  float* hs = (float*)p;

  hipMemsetAsync(hc, 0, 2 * hist_bytes, stream);

  if (fast) {
    vnl_pack<<<(HW + 255) / 256, 256, 0, stream>>>(pred, gt, pk);
    vnl_main4<<<(G + 127) / 128, 128, 0, stream>>>(pk, p1, p2, p3, ubits, G);
  } else {
    vnl_main<<<(N + 255) / 256, 256, 0, stream>>>(pred, gt, p1, p2, p3, ubits, G, N);
  }
  vnl_hist<<<NBH, 256, 0, stream>>>(ubits, hc, hs, N);
  vnl_scanfinal<<<1, 1024, 0, stream>>>(hc, hs, (float*)d_out);
}